// Round 6
// baseline (281.708 us; speedup 1.0000x reference)
//
#include <hip/hip_runtime.h>

#define NROWS 131072
#define D 64
#define K 1024

typedef __attribute__((ext_vector_type(8))) short short8;
typedef __attribute__((ext_vector_type(4))) float f32x4;

// ws layout (bytes):
//   [0, 131072)        ehT  ushort[1024][64]  bf16 hi, [code][d]
//   [131072, 393216)   eTf  float[1024][64]   fp32 codebook transposed
//   [393216, 409600)   e2p  float[4][1024]    partial ||e||^2 sums
//   [409600, 413696)   hist int[1024]
//   [413696, 413700)   lacc float             loss accumulator
//   [413700, 413704)   counter int            finished-block counter

__device__ __forceinline__ unsigned short f2bf(float f) {
    unsigned u = __float_as_uint(f);
    u += 0x7fff + ((u >> 16) & 1);   // round-to-nearest-even
    return (unsigned short)(u >> 16);
}

__global__ __launch_bounds__(256) void prep_kernel(const float* __restrict__ E,
                                                   unsigned short* __restrict__ ehT,
                                                   float* __restrict__ eTf,
                                                   float* __restrict__ e2p,
                                                   int* __restrict__ hist,
                                                   float* __restrict__ lacc,
                                                   int* __restrict__ counter) {
    // 16 blocks x 256: k = (blk&3)*256 + tid, dq = blk>>2 ; thread does d = dq*16..dq*16+15
    const int k = (blockIdx.x & 3) * 256 + threadIdx.x;
    const int dq = blockIdx.x >> 2;
    float f[16];
    float s = 0.f;
#pragma unroll
    for (int j = 0; j < 16; ++j) {
        float v = E[(dq * 16 + j) * K + k];   // coalesced across lanes
        f[j] = v;
        s = fmaf(v, v, s);
    }
    short8 h0, h1;
#pragma unroll
    for (int j = 0; j < 8; ++j) {
        h0[j] = (short)f2bf(f[j]);
        h1[j] = (short)f2bf(f[8 + j]);
    }
    *(short8*)(ehT + (size_t)k * D + dq * 16) = h0;
    *(short8*)(ehT + (size_t)k * D + dq * 16 + 8) = h1;
#pragma unroll
    for (int c = 0; c < 4; ++c) {
        float4 v = {f[c * 4], f[c * 4 + 1], f[c * 4 + 2], f[c * 4 + 3]};
        *(float4*)(eTf + (size_t)k * D + dq * 16 + c * 4) = v;
    }
    e2p[dq * K + k] = s;
    if (dq == 0) hist[k] = 0;
    if (blockIdx.x == 0 && threadIdx.x == 0) { *lacc = 0.f; *counter = 0; }
}

// 256 threads = 4 waves; wave handles 32 rows (2 strips of 16); block = 128 rows.
// grid = 1024 blocks -> 4 blocks/CU (LDS ~34 KB each), 16 waves/CU.
__global__ __launch_bounds__(256, 4) void score_kernel(const float* __restrict__ X,
                                                       const unsigned short* __restrict__ ehT,
                                                       const float* __restrict__ e2p,
                                                       const float* __restrict__ eTf,
                                                       int* __restrict__ hist,
                                                       float* __restrict__ lacc,
                                                       int* __restrict__ counter,
                                                       float* __restrict__ q) {
    __shared__ unsigned short ehs[256 * 64];  // 32 KB, XOR-swizzled [code][unit^(code&7)]
    __shared__ float e2s[256];
    __shared__ int idxs[4][32];
    __shared__ float red[4];
    __shared__ int amLast;

    const int tid = threadIdx.x;
    const int wave = tid >> 6;
    const int lane = tid & 63;
    const int quad = lane >> 4;
    const int lc = lane & 15;
    const size_t row0 = (size_t)blockIdx.x * 128 + wave * 32;

    // staging map for this thread: 8 slots of 16B; slot r -> code c, unit o
    const int so = tid & 7;                       // unit index (0..7)
    // thread's LDS write addrs are fixed per r; global src advances by pass.

    // ---- prefetch pass 0 into registers ----
    short8 pf[8];
#pragma unroll
    for (int r = 0; r < 8; ++r) {
        int c = (r * 256 + tid) >> 3;
        pf[r] = *(const short8*)(ehT + ((size_t)c * D + so * 8));
    }
    float e2a = e2p[tid], e2b = e2p[K + tid], e2c_ = e2p[2 * K + tid], e2d = e2p[3 * K + tid];

    // ---- prologue: A fragments (bf16-hi), A[m=lc][k=quad*8+j] ----
    short8 ax[2][2];
#pragma unroll
    for (int s = 0; s < 2; ++s) {
        const float* xr = X + (row0 + s * 16 + lc) * D;
#pragma unroll
        for (int ks = 0; ks < 2; ++ks) {
            float4 a = *(const float4*)(xr + ks * 32 + quad * 8);
            float4 b = *(const float4*)(xr + ks * 32 + quad * 8 + 4);
            float f[8] = {a.x, a.y, a.z, a.w, b.x, b.y, b.z, b.w};
            short8 h;
#pragma unroll
            for (int j = 0; j < 8; ++j) h[j] = (short)f2bf(f[j]);
            ax[s][ks] = h;
        }
    }

    float best[2][4];
    int bidx[2][4];
#pragma unroll
    for (int s = 0; s < 2; ++s)
#pragma unroll
        for (int r = 0; r < 4; ++r) { best[s][r] = -3.4e38f; bidx[s][r] = 0; }

    // per-lane constant swizzled LDS byte offsets for B fragments
    const int boff0 = lc * 128 + ((quad ^ (lc & 7)) * 16);
    const int boff1 = lc * 128 + (((quad + 4) ^ (lc & 7)) * 16);

    for (int p = 0; p < 4; ++p) {
        if (p) __syncthreads();  // all waves done computing previous pass
        // ---- commit prefetched regs to LDS (vmcnt long satisfied by compute overlap) ----
#pragma unroll
        for (int r = 0; r < 8; ++r) {
            int c = (r * 256 + tid) >> 3;
            *(short8*)((char*)ehs + c * 128 + ((so ^ (c & 7)) * 16)) = pf[r];
        }
        e2s[tid] = -0.5f * (e2a + e2b + e2c_ + e2d);
        // ---- issue prefetch for next pass; lands during compute below ----
        if (p < 3) {
#pragma unroll
            for (int r = 0; r < 8; ++r) {
                int c = (r * 256 + tid) >> 3;
                pf[r] = *(const short8*)(ehT + ((size_t)((p + 1) * 256 + c) * D + so * 8));
            }
            int gk = (p + 1) * 256 + tid;
            e2a = e2p[gk]; e2b = e2p[K + gk]; e2c_ = e2p[2 * K + gk]; e2d = e2p[3 * K + gk];
        }
        __syncthreads();

        // ---- 16 tiles of 16 codes ----
#pragma unroll 4
        for (int t = 0; t < 16; ++t) {
            const int cc = t * 16 + lc;           // code within pass
            const int code = p * 256 + cc;
            short8 eb0 = *(const short8*)((char*)ehs + t * 2048 + boff0);
            short8 eb1 = *(const short8*)((char*)ehs + t * 2048 + boff1);
            float ce2 = e2s[cc];
#pragma unroll
            for (int s = 0; s < 2; ++s) {
                f32x4 acc = {ce2, ce2, ce2, ce2};
                acc = __builtin_amdgcn_mfma_f32_16x16x32_bf16(ax[s][0], eb0, acc, 0, 0, 0);
                acc = __builtin_amdgcn_mfma_f32_16x16x32_bf16(ax[s][1], eb1, acc, 0, 0, 0);
#pragma unroll
                for (int r = 0; r < 4; ++r) {
                    if (acc[r] > best[s][r]) { best[s][r] = acc[r]; bidx[s][r] = code; }
                }
            }
        }
    }

    // ---- merge across the 16 lanes sharing rows ----
#pragma unroll
    for (int off = 1; off <= 8; off <<= 1) {
#pragma unroll
        for (int s = 0; s < 2; ++s)
#pragma unroll
            for (int r = 0; r < 4; ++r) {
                float ob = __shfl_xor(best[s][r], off, 64);
                int oi = __shfl_xor(bidx[s][r], off, 64);
                if (ob > best[s][r] || (ob == best[s][r] && oi < bidx[s][r])) {
                    best[s][r] = ob;
                    bidx[s][r] = oi;
                }
            }
    }

    // ---- wave-local index exchange (same-wave LDS RAW is ordered) ----
    if (lc == 0) {
#pragma unroll
        for (int s = 0; s < 2; ++s)
#pragma unroll
            for (int r = 0; r < 4; ++r)
                idxs[wave][s * 16 + quad * 4 + r] = bidx[s][r];
    }
    if (lane < 32) atomicAdd(&hist[idxs[wave][lane]], 1);

    // ---- coalesced epilogue: 8 iterations x 4 rows (one per quad) ----
    float ls = 0.f;
#pragma unroll 4
    for (int it = 0; it < 8; ++it) {
        int rl = it * 4 + quad;
        int k = idxs[wave][rl];                  // broadcast within quad-group
        size_t row = row0 + rl;
        float4 xv = *(const float4*)(X + row * D + lc * 4);
        float4 ev = *(const float4*)(eTf + (size_t)k * D + lc * 4);
        float4 o;
        float dx = ev.x - xv.x; ls = fmaf(dx, dx, ls); o.x = xv.x + dx;
        float dy = ev.y - xv.y; ls = fmaf(dy, dy, ls); o.y = xv.y + dy;
        float dz = ev.z - xv.z; ls = fmaf(dz, dz, ls); o.z = xv.z + dz;
        float dw = ev.w - xv.w; ls = fmaf(dw, dw, ls); o.w = xv.w + dw;
        *(float4*)(q + row * D + lc * 4) = o;
    }
    for (int off = 32; off > 0; off >>= 1) ls += __shfl_down(ls, off, 64);
    if (lane == 0) red[wave] = ls;
    __syncthreads();
    if (tid == 0) atomicAdd(lacc, red[0] + red[1] + red[2] + red[3]);

    // ---- last-block finalize (device-scope: fence + atomic counter) ----
    __threadfence();
    if (tid == 0) amLast = (atomicAdd(counter, 1) == (int)gridDim.x - 1);
    __syncthreads();
    if (amLast) {
        __threadfence();
        float term = 0.f;
#pragma unroll
        for (int j = 0; j < 4; ++j) {
            int c = atomicAdd(&hist[tid + j * 256], 0);   // device-scope load
            float pp = (float)c * (1.0f / (float)NROWS);
            term += pp * logf(pp + 1e-10f);
        }
        for (int off = 32; off > 0; off >>= 1) term += __shfl_down(term, off, 64);
        if (lane == 0) red[wave] = term;
        __syncthreads();
        if (tid == 0) {
            float H = red[0] + red[1] + red[2] + red[3];
            float L = atomicAdd(lacc, 0.f);               // device-scope load
            float* out = q;
            out[(size_t)NROWS * D + 0] = 2.0f * (L / (float)(NROWS * D));
            out[(size_t)NROWS * D + 1] = expf(-H);
        }
    }
}

extern "C" void kernel_launch(void* const* d_in, const int* in_sizes, int n_in,
                              void* d_out, int out_size, void* d_ws, size_t ws_size,
                              hipStream_t stream) {
    const float* X = (const float*)d_in[0];   // [64,2048,64] fp32
    const float* E = (const float*)d_in[1];   // [64,1024]   fp32
    float* out = (float*)d_out;

    char* w = (char*)d_ws;
    unsigned short* ehT = (unsigned short*)(w + 0);
    float* eTf          = (float*)(w + 131072);
    float* e2p          = (float*)(w + 393216);
    int* hist           = (int*)(w + 409600);
    float* lacc         = (float*)(w + 413696);
    int* counter        = (int*)(w + 413700);

    prep_kernel<<<16, 256, 0, stream>>>(E, ehT, eTf, e2p, hist, lacc, counter);
    score_kernel<<<NROWS / 128, 256, 0, stream>>>(X, ehT, e2p, eTf, hist, lacc, counter, out);
}

// Round 7
// 139.662 us; speedup vs baseline: 2.0171x; 2.0171x over previous
//
#include <hip/hip_runtime.h>

#define NROWS 131072
#define D 64
#define K 1024

typedef __attribute__((ext_vector_type(8))) short short8;
typedef __attribute__((ext_vector_type(4))) float f32x4;

// ws layout (bytes):
//   [0, 131072)        ehT  ushort[1024][64]  bf16 hi, [code][d]
//   [131072, 393216)   eTf  float[1024][64]   fp32 codebook transposed
//   [393216, 409600)   e2p  float[4][1024]    partial ||e||^2 sums
//   [409600, 413696)   hist int[1024]
//   [413696, 430080)   wavesum float[4096]

__device__ __forceinline__ unsigned short f2bf(float f) {
    unsigned u = __float_as_uint(f);
    u += 0x7fff + ((u >> 16) & 1);   // round-to-nearest-even
    return (unsigned short)(u >> 16);
}

__global__ __launch_bounds__(256) void prep_kernel(const float* __restrict__ E,
                                                   unsigned short* __restrict__ ehT,
                                                   float* __restrict__ eTf,
                                                   float* __restrict__ e2p,
                                                   int* __restrict__ hist) {
    // 16 blocks x 256: k = (blk&3)*256 + tid, dq = blk>>2 ; thread does d = dq*16..dq*16+15
    const int k = (blockIdx.x & 3) * 256 + threadIdx.x;
    const int dq = blockIdx.x >> 2;
    float f[16];
    float s = 0.f;
#pragma unroll
    for (int j = 0; j < 16; ++j) {
        float v = E[(dq * 16 + j) * K + k];   // coalesced across lanes
        f[j] = v;
        s = fmaf(v, v, s);
    }
    short8 h0, h1;
#pragma unroll
    for (int j = 0; j < 8; ++j) {
        h0[j] = (short)f2bf(f[j]);
        h1[j] = (short)f2bf(f[8 + j]);
    }
    *(short8*)(ehT + (size_t)k * D + dq * 16) = h0;
    *(short8*)(ehT + (size_t)k * D + dq * 16 + 8) = h1;
#pragma unroll
    for (int c = 0; c < 4; ++c) {
        float4 v = {f[c * 4], f[c * 4 + 1], f[c * 4 + 2], f[c * 4 + 3]};
        *(float4*)(eTf + (size_t)k * D + dq * 16 + c * 4) = v;
    }
    e2p[dq * K + k] = s;
    if (dq == 0) hist[k] = 0;
}

// 256 threads = 4 waves; wave handles 32 rows (2 strips of 16); block = 128 rows.
// grid = 1024 blocks -> 4 blocks/CU (LDS ~34 KB each), 16 waves/CU.
// NOTE (R6 lesson): no __threadfence / fused finalize here — a per-block
// device-scope fence forces L2 writeback on non-coherent XCDs (cost ~150 us).
__global__ __launch_bounds__(256, 4) void score_kernel(const float* __restrict__ X,
                                                       const unsigned short* __restrict__ ehT,
                                                       const float* __restrict__ e2p,
                                                       const float* __restrict__ eTf,
                                                       int* __restrict__ hist,
                                                       float* __restrict__ wavesum,
                                                       float* __restrict__ q) {
    __shared__ unsigned short ehs[256 * 64];  // 32 KB, XOR-swizzled [code][unit^(code&7)]
    __shared__ float e2s[256];
    __shared__ int idxs[4][32];

    const int tid = threadIdx.x;
    const int wave = tid >> 6;
    const int lane = tid & 63;
    const int quad = lane >> 4;
    const int lc = lane & 15;
    const size_t row0 = (size_t)blockIdx.x * 128 + wave * 32;

    const int so = tid & 7;  // 16B unit index within a code row (staging map)

    // ---- prefetch pass 0 into registers ----
    short8 pf[8];
#pragma unroll
    for (int r = 0; r < 8; ++r) {
        int c = (r * 256 + tid) >> 3;
        pf[r] = *(const short8*)(ehT + ((size_t)c * D + so * 8));
    }
    float e2a = e2p[tid], e2b = e2p[K + tid], e2c_ = e2p[2 * K + tid], e2d = e2p[3 * K + tid];

    // ---- prologue: A fragments (bf16-hi), A[m=lc][k=quad*8+j] ----
    short8 ax[2][2];
#pragma unroll
    for (int s = 0; s < 2; ++s) {
        const float* xr = X + (row0 + s * 16 + lc) * D;
#pragma unroll
        for (int ks = 0; ks < 2; ++ks) {
            float4 a = *(const float4*)(xr + ks * 32 + quad * 8);
            float4 b = *(const float4*)(xr + ks * 32 + quad * 8 + 4);
            float f[8] = {a.x, a.y, a.z, a.w, b.x, b.y, b.z, b.w};
            short8 h;
#pragma unroll
            for (int j = 0; j < 8; ++j) h[j] = (short)f2bf(f[j]);
            ax[s][ks] = h;
        }
    }

    float best[2][4];
    int bidx[2][4];
#pragma unroll
    for (int s = 0; s < 2; ++s)
#pragma unroll
        for (int r = 0; r < 4; ++r) { best[s][r] = -3.4e38f; bidx[s][r] = 0; }

    // per-lane constant swizzled LDS byte offsets for B fragments
    const int boff0 = lc * 128 + ((quad ^ (lc & 7)) * 16);
    const int boff1 = lc * 128 + (((quad + 4) ^ (lc & 7)) * 16);

    for (int p = 0; p < 4; ++p) {
        if (p) __syncthreads();  // all waves done computing previous pass
        // ---- commit prefetched regs to LDS (loads landed during previous pass) ----
#pragma unroll
        for (int r = 0; r < 8; ++r) {
            int c = (r * 256 + tid) >> 3;
            *(short8*)((char*)ehs + c * 128 + ((so ^ (c & 7)) * 16)) = pf[r];
        }
        e2s[tid] = -0.5f * (e2a + e2b + e2c_ + e2d);
        // ---- issue prefetch for next pass; lands during compute below ----
        if (p < 3) {
#pragma unroll
            for (int r = 0; r < 8; ++r) {
                int c = (r * 256 + tid) >> 3;
                pf[r] = *(const short8*)(ehT + ((size_t)((p + 1) * 256 + c) * D + so * 8));
            }
            int gk = (p + 1) * 256 + tid;
            e2a = e2p[gk]; e2b = e2p[K + gk]; e2c_ = e2p[2 * K + gk]; e2d = e2p[3 * K + gk];
        }
        __syncthreads();

        // ---- 16 tiles of 16 codes ----
#pragma unroll 4
        for (int t = 0; t < 16; ++t) {
            const int cc = t * 16 + lc;           // code within pass
            const int code = p * 256 + cc;
            short8 eb0 = *(const short8*)((char*)ehs + t * 2048 + boff0);
            short8 eb1 = *(const short8*)((char*)ehs + t * 2048 + boff1);
            float ce2 = e2s[cc];
#pragma unroll
            for (int s = 0; s < 2; ++s) {
                f32x4 acc = {ce2, ce2, ce2, ce2};
                acc = __builtin_amdgcn_mfma_f32_16x16x32_bf16(ax[s][0], eb0, acc, 0, 0, 0);
                acc = __builtin_amdgcn_mfma_f32_16x16x32_bf16(ax[s][1], eb1, acc, 0, 0, 0);
#pragma unroll
                for (int r = 0; r < 4; ++r) {
                    if (acc[r] > best[s][r]) { best[s][r] = acc[r]; bidx[s][r] = code; }
                }
            }
        }
    }

    // ---- merge across the 16 lanes sharing rows ----
#pragma unroll
    for (int off = 1; off <= 8; off <<= 1) {
#pragma unroll
        for (int s = 0; s < 2; ++s)
#pragma unroll
            for (int r = 0; r < 4; ++r) {
                float ob = __shfl_xor(best[s][r], off, 64);
                int oi = __shfl_xor(bidx[s][r], off, 64);
                if (ob > best[s][r] || (ob == best[s][r] && oi < bidx[s][r])) {
                    best[s][r] = ob;
                    bidx[s][r] = oi;
                }
            }
    }

    // ---- wave-local index exchange (same-wave LDS RAW is ordered) ----
    if (lc == 0) {
#pragma unroll
        for (int s = 0; s < 2; ++s)
#pragma unroll
            for (int r = 0; r < 4; ++r)
                idxs[wave][s * 16 + quad * 4 + r] = bidx[s][r];
    }
    if (lane < 32) atomicAdd(&hist[idxs[wave][lane]], 1);

    // ---- coalesced epilogue: 8 iterations x 4 rows (one per quad) ----
    float ls = 0.f;
#pragma unroll 4
    for (int it = 0; it < 8; ++it) {
        int rl = it * 4 + quad;
        int k = idxs[wave][rl];                  // broadcast within quad-group
        size_t row = row0 + rl;
        float4 xv = *(const float4*)(X + row * D + lc * 4);
        float4 ev = *(const float4*)(eTf + (size_t)k * D + lc * 4);
        float4 o;
        float dx = ev.x - xv.x; ls = fmaf(dx, dx, ls); o.x = xv.x + dx;
        float dy = ev.y - xv.y; ls = fmaf(dy, dy, ls); o.y = xv.y + dy;
        float dz = ev.z - xv.z; ls = fmaf(dz, dz, ls); o.z = xv.z + dz;
        float dw = ev.w - xv.w; ls = fmaf(dw, dw, ls); o.w = xv.w + dw;
        *(float4*)(q + row * D + lc * 4) = o;
    }
    for (int off = 32; off > 0; off >>= 1) ls += __shfl_down(ls, off, 64);
    if (lane == 0) wavesum[blockIdx.x * 4 + wave] = ls;
}

__global__ __launch_bounds__(1024) void finalize_kernel(const int* __restrict__ hist,
                                                        const float* __restrict__ wavesum,
                                                        float* __restrict__ out) {
    __shared__ float redH[16], redL[16];
    int tid = threadIdx.x;
    float p = (float)hist[tid] * (1.0f / (float)NROWS);
    float term = p * logf(p + 1e-10f);
    float ls = wavesum[tid] + wavesum[tid + 1024] + wavesum[tid + 2048] + wavesum[tid + 3072];
    for (int off = 32; off > 0; off >>= 1) {
        term += __shfl_down(term, off, 64);
        ls += __shfl_down(ls, off, 64);
    }
    int lane = tid & 63, wid = tid >> 6;
    if (lane == 0) { redH[wid] = term; redL[wid] = ls; }
    __syncthreads();
    if (tid == 0) {
        float H = 0.f, L = 0.f;
#pragma unroll
        for (int i = 0; i < 16; ++i) { H += redH[i]; L += redL[i]; }
        out[(size_t)NROWS * D + 0] = 2.0f * (L / (float)(NROWS * D));
        out[(size_t)NROWS * D + 1] = expf(-H);
    }
}

extern "C" void kernel_launch(void* const* d_in, const int* in_sizes, int n_in,
                              void* d_out, int out_size, void* d_ws, size_t ws_size,
                              hipStream_t stream) {
    const float* X = (const float*)d_in[0];   // [64,2048,64] fp32
    const float* E = (const float*)d_in[1];   // [64,1024]   fp32
    float* out = (float*)d_out;

    char* w = (char*)d_ws;
    unsigned short* ehT = (unsigned short*)(w + 0);
    float* eTf          = (float*)(w + 131072);
    float* e2p          = (float*)(w + 393216);
    int* hist           = (int*)(w + 409600);
    float* wavesum      = (float*)(w + 413696);

    prep_kernel<<<16, 256, 0, stream>>>(E, ehT, eTf, e2p, hist);
    score_kernel<<<NROWS / 128, 256, 0, stream>>>(X, ehT, e2p, eTf, hist, wavesum, out);
    finalize_kernel<<<1, 1024, 0, stream>>>(hist, wavesum, out);
}

// Round 8
// 134.002 us; speedup vs baseline: 2.1023x; 1.0422x over previous
//
#include <hip/hip_runtime.h>

#define NROWS 131072
#define D 64
#define K 1024

typedef __attribute__((ext_vector_type(8))) short short8;
typedef __attribute__((ext_vector_type(4))) float f32x4;
typedef unsigned int u32;

// ws layout (bytes):
//   [0, 131072)        ehT  ushort[1024][64]  bf16 codebook, [code][d]
//   [131072, 135168)   e2g  float[1024]       = -0.5*||e_k||^2
//   [135168, 139264)   hist int[1024]
//   [139264, 155648)   wavesum float[4096]

__device__ __forceinline__ unsigned short f2bf_rne(float f) {
    u32 u = __float_as_uint(f);
    u += 0x7fff + ((u >> 16) & 1);   // round-to-nearest-even
    return (unsigned short)(u >> 16);
}

__global__ __launch_bounds__(256) void prep_kernel(const float* __restrict__ E,
                                                   unsigned short* __restrict__ ehT,
                                                   float* __restrict__ e2g,
                                                   int* __restrict__ hist) {
    const int k = blockIdx.x * 256 + threadIdx.x;   // 4 blocks, one thread per code
    float s = 0.f;
#pragma unroll
    for (int db = 0; db < 8; ++db) {
        short8 h8;
#pragma unroll
        for (int j = 0; j < 8; ++j) {
            float v = E[(db * 8 + j) * K + k];      // coalesced across lanes
            s = fmaf(v, v, s);
            h8[j] = (short)f2bf_rne(v);
        }
        *(short8*)(ehT + (size_t)k * D + db * 8) = h8;
    }
    e2g[k] = -0.5f * s;
    hist[k] = 0;
}

// 256 threads = 4 waves x 32 rows = 128 rows/block; grid 1024 = 4 blocks/CU.
// Codebook streamed in 8 passes of 128 codes via global_load_lds DMA into a
// double-buffered fragment-order LDS layout: addr(code=t*16+lc, unit o) =
// t*2048 + o*256 + lc*16  (conflict-free for DMA scatter and b128 reads).
// NOTE (R6 lesson): no __threadfence / fused finalize — per-block device-scope
// fence forces L2 writeback on non-coherent XCDs (~150 us).
__global__ __launch_bounds__(256, 4) void score_kernel(const float* __restrict__ X,
                                                       const unsigned short* __restrict__ ehT,
                                                       const float* __restrict__ e2g,
                                                       int* __restrict__ hist,
                                                       float* __restrict__ wavesum,
                                                       float* __restrict__ q) {
    __shared__ unsigned short ehs[2][128 * 64];   // 2 x 16 KB
    __shared__ float e2s[2][128];
    __shared__ int idxs[4][32];

    const int tid = threadIdx.x;
    const int wave = tid >> 6;
    const int lane = tid & 63;
    const int quad = lane >> 4;
    const int lc = lane & 15;
    const size_t row0 = (size_t)blockIdx.x * 128 + wave * 32;

    // ---- DMA source byte-offsets for this lane (4 insts x 1 KB per wave) ----
    u32 gofs[4];
    const u32 slotbase = wave * 256 + lane;
#pragma unroll
    for (int i = 0; i < 4; ++i) {
        u32 slot = slotbase + i * 64;
        u32 t = slot >> 7, o = (slot >> 4) & 7, ls = slot & 15;
        gofs[i] = (t * 16 + ls) * 128 + o * 16;   // byte offset within a pass
    }

    // ---- stage pass 0 (drained by the p=0 barrier) ----
#pragma unroll
    for (int i = 0; i < 4; ++i)
        __builtin_amdgcn_global_load_lds(
            (const __attribute__((address_space(1))) u32*)((const char*)ehT + gofs[i]),
            (__attribute__((address_space(3))) u32*)((char*)&ehs[0][0] + wave * 4096 + i * 1024),
            16, 0, 0);
    if (tid < 128) e2s[0][tid] = e2g[tid];

    // ---- prologue: A fragments, truncation bf16 pack via v_perm ----
    short8 ax[2][2];
#pragma unroll
    for (int s = 0; s < 2; ++s) {
        const float* xr = X + (row0 + s * 16 + lc) * D + quad * 8;
#pragma unroll
        for (int ks = 0; ks < 2; ++ks) {
            float4 a = *(const float4*)(xr + ks * 32);
            float4 b = *(const float4*)(xr + ks * 32 + 4);
            union { u32 u[4]; short8 v; } pk;
            pk.u[0] = __builtin_amdgcn_perm(__float_as_uint(a.y), __float_as_uint(a.x), 0x07060302);
            pk.u[1] = __builtin_amdgcn_perm(__float_as_uint(a.w), __float_as_uint(a.z), 0x07060302);
            pk.u[2] = __builtin_amdgcn_perm(__float_as_uint(b.y), __float_as_uint(b.x), 0x07060302);
            pk.u[3] = __builtin_amdgcn_perm(__float_as_uint(b.w), __float_as_uint(b.z), 0x07060302);
            ax[s][ks] = pk.v;
        }
    }

    // packed (score | code) running max; low 10 mantissa bits hold the code
    float best[2][4];
#pragma unroll
    for (int s = 0; s < 2; ++s)
#pragma unroll
        for (int r = 0; r < 4; ++r) best[s][r] = -3.4e38f;

    const int roff0 = quad * 256 + lc * 16;   // eb0 byte offset within a tile

    for (int p = 0; p < 8; ++p) {
        const int cur = p & 1;
        __syncthreads();   // drains this wave's DMA for pass p; all waves done with p-1
        if (p < 7) {
            const int nxt = (p + 1) & 1;
            const u32 gbase = (u32)(p + 1) * 16384;
#pragma unroll
            for (int i = 0; i < 4; ++i)
                __builtin_amdgcn_global_load_lds(
                    (const __attribute__((address_space(1))) u32*)((const char*)ehT + gbase + gofs[i]),
                    (__attribute__((address_space(3))) u32*)((char*)&ehs[nxt][0] + wave * 4096 + i * 1024),
                    16, 0, 0);
            if (tid < 128) e2s[nxt][tid] = e2g[(p + 1) * 128 + tid];
        }
        const char* bb = (const char*)&ehs[cur][0];
#pragma unroll 2
        for (int t = 0; t < 8; ++t) {
            short8 eb0 = *(const short8*)(bb + t * 2048 + roff0);
            short8 eb1 = *(const short8*)(bb + t * 2048 + 1024 + roff0);
            float ce2 = e2s[cur][t * 16 + lc];
            u32 cb = (u32)(p * 128 + t * 16 + lc);
#pragma unroll
            for (int s = 0; s < 2; ++s) {
                f32x4 acc = {ce2, ce2, ce2, ce2};
                acc = __builtin_amdgcn_mfma_f32_16x16x32_bf16(ax[s][0], eb0, acc, 0, 0, 0);
                acc = __builtin_amdgcn_mfma_f32_16x16x32_bf16(ax[s][1], eb1, acc, 0, 0, 0);
#pragma unroll
                for (int r = 0; r < 4; ++r) {
                    float pkv = __uint_as_float((__float_as_uint(acc[r]) & 0xFFFFFC00u) | cb);
                    best[s][r] = fmaxf(best[s][r], pkv);   // v_and_or + v_max
                }
            }
        }
    }

    // ---- merge across the 16 lanes sharing rows: packed max is order-consistent ----
#pragma unroll
    for (int off = 1; off <= 8; off <<= 1)
#pragma unroll
        for (int s = 0; s < 2; ++s)
#pragma unroll
            for (int r = 0; r < 4; ++r)
                best[s][r] = fmaxf(best[s][r], __shfl_xor(best[s][r], off, 64));

    // ---- wave-local index exchange (same-wave LDS RAW is ordered) ----
    if (lc == 0) {
#pragma unroll
        for (int s = 0; s < 2; ++s)
#pragma unroll
            for (int r = 0; r < 4; ++r)
                idxs[wave][s * 16 + quad * 4 + r] = (int)(__float_as_uint(best[s][r]) & 1023u);
    }
    if (lane < 32) atomicAdd(&hist[idxs[wave][lane]], 1);

    // ---- coalesced epilogue: 8 iters x 4 rows; e gathered from bf16 codebook ----
    float ls = 0.f;
#pragma unroll 4
    for (int it = 0; it < 8; ++it) {
        int rl = it * 4 + quad;
        int k = idxs[wave][rl];                   // broadcast within quad-group
        size_t row = row0 + rl;
        float4 xv = *(const float4*)(X + row * D + lc * 4);
        short4 ev = *(const short4*)((const char*)ehT + (size_t)k * 128 + lc * 8);
        float e0 = __uint_as_float(((u32)(unsigned short)ev.x) << 16);
        float e1 = __uint_as_float(((u32)(unsigned short)ev.y) << 16);
        float e2 = __uint_as_float(((u32)(unsigned short)ev.z) << 16);
        float e3 = __uint_as_float(((u32)(unsigned short)ev.w) << 16);
        float4 o;
        float dx = e0 - xv.x; ls = fmaf(dx, dx, ls); o.x = xv.x + dx;
        float dy = e1 - xv.y; ls = fmaf(dy, dy, ls); o.y = xv.y + dy;
        float dz = e2 - xv.z; ls = fmaf(dz, dz, ls); o.z = xv.z + dz;
        float dw = e3 - xv.w; ls = fmaf(dw, dw, ls); o.w = xv.w + dw;
        *(float4*)(q + row * D + lc * 4) = o;
    }
    for (int off = 32; off > 0; off >>= 1) ls += __shfl_down(ls, off, 64);
    if (lane == 0) wavesum[blockIdx.x * 4 + wave] = ls;
}

__global__ __launch_bounds__(1024) void finalize_kernel(const int* __restrict__ hist,
                                                        const float* __restrict__ wavesum,
                                                        float* __restrict__ out) {
    __shared__ float redH[16], redL[16];
    int tid = threadIdx.x;
    float p = (float)hist[tid] * (1.0f / (float)NROWS);
    float term = p * logf(p + 1e-10f);
    float ls = wavesum[tid] + wavesum[tid + 1024] + wavesum[tid + 2048] + wavesum[tid + 3072];
    for (int off = 32; off > 0; off >>= 1) {
        term += __shfl_down(term, off, 64);
        ls += __shfl_down(ls, off, 64);
    }
    int lane = tid & 63, wid = tid >> 6;
    if (lane == 0) { redH[wid] = term; redL[wid] = ls; }
    __syncthreads();
    if (tid == 0) {
        float H = 0.f, L = 0.f;
#pragma unroll
        for (int i = 0; i < 16; ++i) { H += redH[i]; L += redL[i]; }
        out[(size_t)NROWS * D + 0] = 2.0f * (L / (float)(NROWS * D));
        out[(size_t)NROWS * D + 1] = expf(-H);
    }
}

extern "C" void kernel_launch(void* const* d_in, const int* in_sizes, int n_in,
                              void* d_out, int out_size, void* d_ws, size_t ws_size,
                              hipStream_t stream) {
    const float* X = (const float*)d_in[0];   // [64,2048,64] fp32
    const float* E = (const float*)d_in[1];   // [64,1024]   fp32
    float* out = (float*)d_out;

    char* w = (char*)d_ws;
    unsigned short* ehT = (unsigned short*)(w + 0);
    float* e2g          = (float*)(w + 131072);
    int* hist           = (int*)(w + 135168);
    float* wavesum      = (float*)(w + 139264);

    prep_kernel<<<4, 256, 0, stream>>>(E, ehT, e2g, hist);
    score_kernel<<<NROWS / 128, 256, 0, stream>>>(X, ehT, e2g, hist, wavesum, out);
    finalize_kernel<<<1, 1024, 0, stream>>>(hist, wavesum, out);
}